// Round 8
// baseline (463.243 us; speedup 1.0000x reference)
//
#include <hip/hip_runtime.h>
#include <math.h>

#define N_NODES 50000
#define N_EDGES 1600000
#define F_IN    256
#define DIMS    64
#define N_CLS   16
#define R_REL   8
#define CAP     96          // per-destination CSR capacity (in-deg ~Poisson(32))

// prep: 12500 cvt_x + 3125 csr(half A) interleaved 4:1, + 576 cvt_w tail
#define CVT_BLKS  12500
#define CSRH      3125
#define CVTW_BLKS 576
#define PREP_BLKS (CVT_BLKS + CSRH + CVTW_BLKS)   // 16201
// front: 3519 proj + 3125 csr(half B); first 6250 bids alternate, tail = proj
#define PROJ_BLKS 3519
#define FRONT_BLKS (PROJ_BLKS + CSRH)             // 6644

typedef short bf16x8 __attribute__((ext_vector_type(8)));
typedef float f32x4  __attribute__((ext_vector_type(4)));
typedef unsigned int u32;
typedef const __attribute__((address_space(1))) u32* gas_ptr;
typedef __attribute__((address_space(3))) u32* las_ptr;

__device__ __forceinline__ void async16(const void* g, void* l) {
    __builtin_amdgcn_global_load_lds((gas_ptr)g, (las_ptr)l, 16, 0, 0);
}

__device__ __forceinline__ unsigned short f2bf(float f) {
    unsigned u = __float_as_uint(f);
    unsigned r = (u + 0x7fffu + ((u >> 16) & 1u)) >> 16;
    return (unsigned short)r;
}
__device__ __forceinline__ float bf2f(unsigned short u) {
    return __uint_as_float(((unsigned)u) << 16);
}

__device__ __forceinline__ void csr_edge(
        int e, const int* __restrict__ ei, const int* __restrict__ ecol,
        const float* __restrict__ ew, int* __restrict__ fill,
        unsigned long long* __restrict__ rec) {
    int s = ei[e], d = ei[N_EDGES + e], c = ecol[e];
    float w_ = ew[e];
    int p = atomicAdd(&fill[d], 1);
    int idx = (p < CAP) ? d * CAP + p : N_NODES * CAP;   // overflow dump
    unsigned long long rv =
        ((unsigned long long)__float_as_uint(w_) << 32)
        | (unsigned)(s | (c << 16));
    __builtin_nontemporal_store(rv, &rec[idx]);
}

// ---------- prep: cvt_x + csr half A + cvt_w, one mixed grid ----------
__global__ __launch_bounds__(256) void prep_kernel(
        const float* __restrict__ x, ushort* __restrict__ xb,
        const float* __restrict__ W1, const float* __restrict__ root1,
        ushort* __restrict__ wt1,
        const int* __restrict__ ei, const int* __restrict__ ecol,
        const float* __restrict__ ew, int* __restrict__ fill,
        unsigned long long* __restrict__ rec) {
    const int bid = blockIdx.x;
    const int t = threadIdx.x;
    if (bid < CVT_BLKS + CSRH) {                   // 15625 = 3125 groups of 5
        int g = bid / 5, m = bid - g * 5;
        if (m == 4) {                              // csr half A
            csr_edge(g * 256 + t, ei, ecol, ew, fill, rec);
        } else {                                   // cvt_x
            int i4 = (g * 4 + m) * 256 + t;
            float4 v = ((const float4*)x)[i4];
            ushort4 o;
            o.x = f2bf(v.x); o.y = f2bf(v.y); o.z = f2bf(v.z); o.w = f2bf(v.w);
            ((ushort4*)xb)[i4] = o;
        }
    } else {                                       // cvt_w: wt1[r][n][k], slot 8 = root1
        int idx = (bid - (CVT_BLKS + CSRH)) * 256 + t;   // < 147456
        int r = idx >> 14, rem = idx & 16383;
        int n = rem >> 8, k = rem & 255;
        float v = (r < 8) ? W1[((size_t)r * F_IN + k) * DIMS + n]
                          : root1[(size_t)k * DIMS + n];
        wt1[idx] = f2bf(v);
    }
}

// ---------- front: proj1 MFMA (+si/sj, +x@root1 bf16) AND csr half B ----------
#define BM 128
__global__ __launch_bounds__(256, 6) void front_kernel(
        const ushort* __restrict__ xb, const ushort* __restrict__ wt1,
        const float* __restrict__ at1,
        ushort* __restrict__ xr1b, ushort* __restrict__ hrootb,
        float* __restrict__ si1, float* __restrict__ sj1,
        const int* __restrict__ ei, const int* __restrict__ ecol,
        const float* __restrict__ ew, int* __restrict__ fill,
        unsigned long long* __restrict__ rec) {
    __shared__ ushort xs[BM * 64];                 // 16 KB, swizzled [row][k8^(row&7)]
    const int bid = blockIdx.x;
    const int t = threadIdx.x;

    int pb = -1, cb = -1;
    if (bid < 2 * CSRH) { if (bid & 1) cb = bid >> 1; else pb = bid >> 1; }
    else pb = CSRH + (bid - 2 * CSRH);

    if (cb >= 0) {
        csr_edge(800000 + cb * 256 + t, ei, ecol, ew, fill, rec);
        return;
    }

    // ----- proj1 MFMA branch -----
    const int r = pb / 391;
    const int node0 = (pb % 391) * BM;
    const ushort* wrow = wt1 + (size_t)r * 64 * 256;   // [n][k], L1/L2-resident

    const int w = t >> 6, lane = t & 63;
    const int lane15 = lane & 15, quad = lane >> 4;
    const int row0 = w * 32 + lane15;
    const int sw0 = row0 & 7;

    f32x4 acc[2][4];
    #pragma unroll
    for (int a = 0; a < 2; ++a)
        #pragma unroll
        for (int b = 0; b < 4; ++b)
            acc[a][b] = (f32x4){0.f, 0.f, 0.f, 0.f};

    for (int s = 0; s < 4; ++s) {                  // K staged 4 x 64
        __syncthreads();
        #pragma unroll
        for (int c = 0; c < 4; ++c) {              // 4 x 1024 lane-slots of 16B
            int slot = c * 256 + t;
            int row = slot >> 3, k8p = slot & 7;
            int k8 = k8p ^ (row & 7);              // source-side swizzle
            int node = node0 + row;
            if (node >= N_NODES) node = N_NODES - 1;   // clamp (rows discarded)
            async16(&xb[(size_t)node * 256 + s * 64 + k8 * 8],
                    &xs[(c * 256 + w * 64) * 8]);
        }
        __syncthreads();
        #pragma unroll
        for (int kk = 0; kk < 2; ++kk) {
            int k8 = kk * 4 + quad;
            int aidx = row0 * 64 + ((k8 ^ sw0) << 3);
            bf16x8 a0 = *(const bf16x8*)&xs[aidx];
            bf16x8 a1 = *(const bf16x8*)&xs[aidx + 16 * 64];
            int kg = s * 64 + kk * 32 + quad * 8;
            #pragma unroll
            for (int nt = 0; nt < 4; ++nt) {
                bf16x8 b = *(const bf16x8*)&wrow[(size_t)(nt * 16 + lane15) * 256 + kg];
                acc[0][nt] = __builtin_amdgcn_mfma_f32_16x16x32_bf16(a0, b, acc[0][nt], 0, 0, 0);
                acc[1][nt] = __builtin_amdgcn_mfma_f32_16x16x32_bf16(a1, b, acc[1][nt], 0, 0, 0);
            }
        }
    }

    const float* at = at1 + r * 128;
    #pragma unroll
    for (int mt = 0; mt < 2; ++mt) {
        float pi[4] = {0.f, 0.f, 0.f, 0.f};
        float pj[4] = {0.f, 0.f, 0.f, 0.f};
        #pragma unroll
        for (int nt = 0; nt < 4; ++nt) {
            int gcol = nt * 16 + lane15;
            float ai = 0.f, aj = 0.f;
            if (r < 8) { ai = at[gcol]; aj = at[64 + gcol]; }
            #pragma unroll
            for (int reg = 0; reg < 4; ++reg) {
                float v = acc[mt][nt][reg];
                int grow = node0 + w * 32 + mt * 16 + quad * 4 + reg;
                if (grow < N_NODES) {
                    if (r < 8)
                        xr1b[((size_t)r * N_NODES + grow) * 64 + gcol] = f2bf(v);
                    else
                        hrootb[(size_t)grow * 64 + gcol] = f2bf(v);
                }
                pi[reg] += ai * v;
                pj[reg] += aj * v;
            }
        }
        if (r < 8) {
            #pragma unroll
            for (int reg = 0; reg < 4; ++reg) {
                float s_ = pi[reg], u_ = pj[reg];
                #pragma unroll
                for (int off = 1; off < 16; off <<= 1) {
                    s_ += __shfl_xor(s_, off, 64);
                    u_ += __shfl_xor(u_, off, 64);
                }
                if (lane15 == 0) {
                    int grow = node0 + w * 32 + mt * 16 + quad * 4 + reg;
                    if (grow < N_NODES) {
                        si1[r * N_NODES + grow] = s_;
                        sj1[r * N_NODES + grow] = u_;
                    }
                }
            }
        }
    }
}

// ---------- layer 1: score + aggregate + finalize + FUSED proj2/si2/sj2 ----------
__global__ __launch_bounds__(256) void agg1s_kernel(
        const unsigned long long* __restrict__ rec, const int* __restrict__ fill,
        const float* __restrict__ si, const float* __restrict__ sj,
        const ushort* __restrict__ xr1b, const ushort* __restrict__ hrootb,
        const float* __restrict__ bias1, ushort* __restrict__ hb,
        const float* __restrict__ W2, const float* __restrict__ at2,
        ushort* __restrict__ xr2b, float* __restrict__ si2,
        float* __restrict__ sj2) {
    __shared__ int   esrc[4][CAP];
    __shared__ float ecoef[4][CAP];
    __shared__ float hval[4][64];
    __shared__ float sden[4][8];
    __shared__ int   scnt[4][8];
    __shared__ float ssi[4][8];
    const int t = threadIdx.x;
    const int w = t >> 6, lane = t & 63;
    const int d = blockIdx.x * 4 + w;              // 12500*4 == N_NODES
    if (lane < 8) {
        sden[w][lane] = 0.f; scnt[w][lane] = 0;
        ssi[w][lane] = si[lane * N_NODES + d];
    }
    const int n = min(fill[d], CAP);
    const int base = d * CAP;
    float ex[2] = {0.f, 0.f}, ww[2] = {0.f, 0.f};
    int cc[2] = {0, 0};
    #pragma unroll
    for (int ii = 0; ii < 2; ++ii) {
        int i = lane + ii * 64;
        if (i < n) {
            unsigned long long rv = rec[base + i];
            int px = (int)(unsigned)rv;
            int s = px & 0xffff, c = (px >> 16) & 0x7fff;
            esrc[w][i] = px;
            float sc = ssi[w][c] + sj[c * N_NODES + s];
            sc = sc > 0.f ? sc : 0.2f * sc;
            float e = __expf(sc);
            ex[ii] = e; cc[ii] = c; ww[ii] = __uint_as_float((unsigned)(rv >> 32));
            atomicAdd(&sden[w][c], e);
            atomicAdd(&scnt[w][c], 1);
        }
    }
    #pragma unroll
    for (int ii = 0; ii < 2; ++ii) {
        int i = lane + ii * 64;
        if (i < n)
            ecoef[w][i] = ex[ii] / fmaxf(sden[w][cc[ii]], 1e-16f)
                          * ww[ii] / (float)scnt[w][cc[ii]];
    }
    // gather phase (wave-private LDS; in-order DS queue -> no barrier)
    float a0 = 0.f, a1 = 0.f, a2 = 0.f, a3 = 0.f;
    int i = 0;
    for (; i + 4 <= n; i += 4) {
        int p0 = esrc[w][i], p1 = esrc[w][i + 1];
        int p2 = esrc[w][i + 2], p3 = esrc[w][i + 3];
        float c0 = ecoef[w][i], c1 = ecoef[w][i + 1];
        float c2 = ecoef[w][i + 2], c3 = ecoef[w][i + 3];
        int r0 = (p0 >> 16) * N_NODES + (p0 & 0xffff);
        int r1 = (p1 >> 16) * N_NODES + (p1 & 0xffff);
        int r2 = (p2 >> 16) * N_NODES + (p2 & 0xffff);
        int r3 = (p3 >> 16) * N_NODES + (p3 & 0xffff);
        a0 += c0 * bf2f(xr1b[(size_t)r0 * 64 + lane]);
        a1 += c1 * bf2f(xr1b[(size_t)r1 * 64 + lane]);
        a2 += c2 * bf2f(xr1b[(size_t)r2 * 64 + lane]);
        a3 += c3 * bf2f(xr1b[(size_t)r3 * 64 + lane]);
    }
    for (; i < n; ++i) {
        int p0 = esrc[w][i];
        int r0 = (p0 >> 16) * N_NODES + (p0 & 0xffff);
        a0 += ecoef[w][i] * bf2f(xr1b[(size_t)r0 * 64 + lane]);
    }
    float hf = (a0 + a1) + (a2 + a3)
               + bf2f(hrootb[(size_t)d * 64 + lane]) + bias1[lane];
    hf = fmaxf(hf, 0.f);
    hb[(size_t)d * 64 + lane] = f2bf(hf);
    hval[w][lane] = hf;
    // ---- fused proj2: lane -> (r=lane>>4, c=lane&15) and (r+4, c) ----
    const int r_ = lane >> 4, c_ = lane & 15;
    float v0 = 0.f, v1 = 0.f;
    #pragma unroll 8
    for (int k = 0; k < 64; ++k) {
        float hk = hval[w][k];
        v0 += hk * W2[((size_t)r_ * 64 + k) * 16 + c_];
        v1 += hk * W2[((size_t)(r_ + 4) * 64 + k) * 16 + c_];
    }
    xr2b[((size_t)r_ * N_NODES + d) * 16 + c_] = f2bf(v0);
    xr2b[((size_t)(r_ + 4) * N_NODES + d) * 16 + c_] = f2bf(v1);
    float s0 = at2[r_ * 32 + c_] * v0,        j0 = at2[r_ * 32 + 16 + c_] * v0;
    float s1 = at2[(r_ + 4) * 32 + c_] * v1,  j1 = at2[(r_ + 4) * 32 + 16 + c_] * v1;
    #pragma unroll
    for (int off = 1; off < 16; off <<= 1) {
        s0 += __shfl_xor(s0, off, 64); j0 += __shfl_xor(j0, off, 64);
        s1 += __shfl_xor(s1, off, 64); j1 += __shfl_xor(j1, off, 64);
    }
    if (c_ == 0) {
        si2[r_ * N_NODES + d] = s0;       sj2[r_ * N_NODES + d] = j0;
        si2[(r_ + 4) * N_NODES + d] = s1; sj2[(r_ + 4) * N_NODES + d] = j1;
    }
}

// ---------- layer 2: fused score + aggregate + root2 + log_softmax ----------
__global__ __launch_bounds__(256) void agg2s_kernel(
        const unsigned long long* __restrict__ rec, const int* __restrict__ fill,
        const float* __restrict__ si, const float* __restrict__ sj,
        const ushort* __restrict__ xr2b, const ushort* __restrict__ hb,
        const float* __restrict__ root2, const float* __restrict__ bias2,
        float* __restrict__ out) {
    __shared__ float rsh[64][17];
    __shared__ float hsh[4][64];
    __shared__ int   esrc[4][CAP];
    __shared__ float ecoef[4][CAP];
    __shared__ float sden[4][8];
    __shared__ int   scnt[4][8];
    __shared__ float ssi[4][8];
    const int t = threadIdx.x;
    for (int i = t; i < DIMS * N_CLS; i += 256) rsh[i >> 4][i & 15] = root2[i];
    const int w = t >> 6, lane = t & 63;
    const int d = blockIdx.x * 4 + w;
    hsh[w][lane] = bf2f(hb[(size_t)d * 64 + lane]);
    if (lane < 8) {
        sden[w][lane] = 0.f; scnt[w][lane] = 0;
        ssi[w][lane] = si[lane * N_NODES + d];
    }
    const int n = min(fill[d], CAP);
    const int base = d * CAP;
    float ex[2] = {0.f, 0.f}, ww[2] = {0.f, 0.f};
    int cc[2] = {0, 0};
    #pragma unroll
    for (int ii = 0; ii < 2; ++ii) {
        int i = lane + ii * 64;
        if (i < n) {
            unsigned long long rv = rec[base + i];
            int px = (int)(unsigned)rv;
            int s = px & 0xffff, c = (px >> 16) & 0x7fff;
            esrc[w][i] = px;
            float sc = ssi[w][c] + sj[c * N_NODES + s];
            sc = sc > 0.f ? sc : 0.2f * sc;
            float e = __expf(sc);
            ex[ii] = e; cc[ii] = c; ww[ii] = __uint_as_float((unsigned)(rv >> 32));
            atomicAdd(&sden[w][c], e);
            atomicAdd(&scnt[w][c], 1);
        }
    }
    #pragma unroll
    for (int ii = 0; ii < 2; ++ii) {
        int i = lane + ii * 64;
        if (i < n)
            ecoef[w][i] = ex[ii] / fmaxf(sden[w][cc[ii]], 1e-16f)
                          * ww[ii] / (float)scnt[w][cc[ii]];
    }
    __syncthreads();                               // rsh cooperative load
    const int sub = lane >> 4, cd = lane & 15;
    float acc = 0.f;
    for (int i = sub; i < n; i += 4) {
        int p = esrc[w][i];
        int row = (p >> 16) * N_NODES + (p & 0xffff);
        acc += ecoef[w][i] * bf2f(xr2b[(size_t)row * 16 + cd]);
    }
    #pragma unroll
    for (int k0 = 0; k0 < 16; ++k0) {              // root2 contribution
        int k = sub * 16 + k0;
        acc += hsh[w][k] * rsh[k][cd];
    }
    acc += __shfl_xor(acc, 16, 64);
    acc += __shfl_xor(acc, 32, 64);
    if (sub == 0) {
        acc += bias2[cd];
        float m = acc;
        #pragma unroll
        for (int off = 8; off; off >>= 1) m = fmaxf(m, __shfl_xor(m, off, 16));
        float ex2 = expf(acc - m);
        float ssum = ex2;
        #pragma unroll
        for (int off = 8; off; off >>= 1) ssum += __shfl_xor(ssum, off, 16);
        out[(size_t)d * 16 + cd] = acc - m - logf(ssum);
    }
}

extern "C" void kernel_launch(void* const* d_in, const int* in_sizes, int n_in,
                              void* d_out, int out_size, void* d_ws, size_t ws_size,
                              hipStream_t stream) {
    const float* x     = (const float*)d_in[0];
    const int*   ei    = (const int*)  d_in[1];
    const float* ew    = (const float*)d_in[2];
    const int*   ecol  = (const int*)  d_in[3];
    const float* W1    = (const float*)d_in[4];
    const float* at1   = (const float*)d_in[5];
    const float* root1 = (const float*)d_in[6];
    const float* b1    = (const float*)d_in[7];
    const float* W2    = (const float*)d_in[8];
    const float* at2   = (const float*)d_in[9];
    const float* root2 = (const float*)d_in[10];
    const float* b2    = (const float*)d_in[11];
    float* out = (float*)d_out;
    float* ws  = (float*)d_ws;

    // workspace layout (float offsets)
    ushort*   xb    = (ushort*)(ws + 0);           // 12.8M bf16
    ushort*   wt1   = (ushort*)(ws + 6400000);     // 147,456 bf16 [9][64][256]
    ushort*   xr1b  = (ushort*)(ws + 6480000);     // 25.6M bf16 [R,N,64]
    ushort*   hrootb= (ushort*)(ws + 19280000);    // 3.2M bf16
    ushort*   xr2b  = (ushort*)(ws + 20880000);    // 6.4M bf16 [R,N,16]
    float*    si1   = ws + 24080000;               // 400k
    float*    sj1   = ws + 24480000;               // 400k
    float*    si2   = ws + 24880000;               // 400k
    float*    sj2   = ws + 25280000;               // 400k
    int*      fill  = (int*)(ws + 25680000);       // 50k, zeroed
    ushort*   hb    = (ushort*)(ws + 25730000);    // 3.2M bf16
    unsigned long long* rec = (unsigned long long*)(ws + 27330000); // 4.8M+1 u64

    hipMemsetAsync(fill, 0, (size_t)N_NODES * 4, stream);

    prep_kernel<<<PREP_BLKS, 256, 0, stream>>>(x, xb, W1, root1, wt1,
                                               ei, ecol, ew, fill, rec);
    front_kernel<<<FRONT_BLKS, 256, 0, stream>>>(xb, wt1, at1, xr1b, hrootb,
                                                 si1, sj1, ei, ecol, ew, fill, rec);
    agg1s_kernel<<<12500, 256, 0, stream>>>(rec, fill, si1, sj1, xr1b, hrootb,
                                            b1, hb, W2, at2, xr2b, si2, sj2);
    agg2s_kernel<<<12500, 256, 0, stream>>>(rec, fill, si2, sj2, xr2b, hb,
                                            root2, b2, out);
}

// Round 9
// 434.257 us; speedup vs baseline: 1.0667x; 1.0667x over previous
//
#include <hip/hip_runtime.h>
#include <math.h>

#define N_NODES 50000
#define N_EDGES 1600000
#define F_IN    256
#define DIMS    64
#define N_CLS   16
#define R_REL   8
#define CAP     96          // per-destination CSR capacity (in-deg ~Poisson(32))

#define PROJ_BLKS 3519      // 391 tiles x 9 "relations" (8 + root slot)
#define CSR_BLKS  6250
#define FRONT_BLKS (PROJ_BLKS + CSR_BLKS)

typedef short bf16x8 __attribute__((ext_vector_type(8)));
typedef float f32x4  __attribute__((ext_vector_type(4)));
typedef unsigned int u32;
typedef const __attribute__((address_space(1))) u32* gas_ptr;
typedef __attribute__((address_space(3))) u32* las_ptr;

__device__ __forceinline__ void async16(const void* g, void* l) {
    __builtin_amdgcn_global_load_lds((gas_ptr)g, (las_ptr)l, 16, 0, 0);
}

__device__ __forceinline__ unsigned short f2bf(float f) {
    unsigned u = __float_as_uint(f);
    unsigned r = (u + 0x7fffu + ((u >> 16) & 1u)) >> 16;
    return (unsigned short)r;
}
__device__ __forceinline__ float bf2f(unsigned short u) {
    return __uint_as_float(((unsigned)u) << 16);
}

// rec record: c[31:29] | s[28:12] | ew_q[11:0]  (ew in [0,1), 12-bit quant)
__device__ __forceinline__ void csr_edge(
        int e, const int* __restrict__ ei, const int* __restrict__ ecol,
        const float* __restrict__ ew, int* __restrict__ fill,
        u32* __restrict__ rec) {
    int s = ei[e], d = ei[N_EDGES + e], c = ecol[e];
    float w_ = ew[e];
    int ewq = (int)(w_ * 4096.f);
    if (ewq > 4095) ewq = 4095;
    int p = atomicAdd(&fill[d], 1);
    int idx = (p < CAP) ? d * CAP + p : N_NODES * CAP;   // overflow dump
    u32 rv = ((u32)c << 29) | ((u32)s << 12) | (u32)ewq;
    __builtin_nontemporal_store(rv, &rec[idx]);
}

// ---------- convert x -> bf16 ----------
__global__ __launch_bounds__(256) void cvt_x_kernel(
        const float* __restrict__ x, ushort* __restrict__ xb) {
    int i4 = blockIdx.x * 256 + threadIdx.x;       // 3.2M quads
    float4 v = ((const float4*)x)[i4];
    ushort4 o;
    o.x = f2bf(v.x); o.y = f2bf(v.y); o.z = f2bf(v.z); o.w = f2bf(v.w);
    ((ushort4*)xb)[i4] = o;
}

// ---------- build wt1[r][n][k] bf16 (transposed, slot 8 = root1) ----------
__global__ __launch_bounds__(256) void cvt_w_kernel(
        const float* __restrict__ W1, const float* __restrict__ root1,
        ushort* __restrict__ wt1) {
    int idx = blockIdx.x * 256 + threadIdx.x;      // 9*64*256 = 147456
    int r = idx >> 14, rem = idx & 16383;
    int n = rem >> 8, k = rem & 255;
    float v = (r < 8) ? W1[((size_t)r * F_IN + k) * DIMS + n]
                      : root1[(size_t)k * DIMS + n];
    wt1[idx] = f2bf(v);
}

// ---------- front: proj1 MFMA (+si/sj, +x@root1 bf16) AND full CSR build ----------
#define BM 128
__global__ __launch_bounds__(256, 6) void front_kernel(
        const ushort* __restrict__ xb, const ushort* __restrict__ wt1,
        const float* __restrict__ at1,
        ushort* __restrict__ xr1b, ushort* __restrict__ hrootb,
        float* __restrict__ si1, float* __restrict__ sj1,
        const int* __restrict__ ei, const int* __restrict__ ecol,
        const float* __restrict__ ew, int* __restrict__ fill,
        u32* __restrict__ rec) {
    __shared__ ushort xs[BM * 64];                 // 16 KB, swizzled [row][k8^(row&7)]
    const int bid = blockIdx.x;
    const int t = threadIdx.x;

    int pb = -1, cb = -1;
    if (bid < 2 * PROJ_BLKS) { if (bid & 1) cb = bid >> 1; else pb = bid >> 1; }
    else cb = PROJ_BLKS + (bid - 2 * PROJ_BLKS);

    if (cb >= 0) {
        csr_edge(cb * 256 + t, ei, ecol, ew, fill, rec);
        return;
    }

    // ----- proj1 MFMA branch -----
    const int r = pb / 391;
    const int node0 = (pb % 391) * BM;
    const ushort* wrow = wt1 + (size_t)r * 64 * 256;   // [n][k], L1/L2-resident

    const int w = t >> 6, lane = t & 63;
    const int lane15 = lane & 15, quad = lane >> 4;
    const int row0 = w * 32 + lane15;
    const int sw0 = row0 & 7;

    f32x4 acc[2][4];
    #pragma unroll
    for (int a = 0; a < 2; ++a)
        #pragma unroll
        for (int b = 0; b < 4; ++b)
            acc[a][b] = (f32x4){0.f, 0.f, 0.f, 0.f};

    for (int s = 0; s < 4; ++s) {                  // K staged 4 x 64
        __syncthreads();
        #pragma unroll
        for (int c = 0; c < 4; ++c) {              // 4 x 1024 lane-slots of 16B
            int slot = c * 256 + t;
            int row = slot >> 3, k8p = slot & 7;
            int k8 = k8p ^ (row & 7);              // source-side swizzle
            int node = node0 + row;
            if (node >= N_NODES) node = N_NODES - 1;   // clamp (rows discarded)
            async16(&xb[(size_t)node * 256 + s * 64 + k8 * 8],
                    &xs[(c * 256 + w * 64) * 8]);
        }
        __syncthreads();
        #pragma unroll
        for (int kk = 0; kk < 2; ++kk) {
            int k8 = kk * 4 + quad;
            int aidx = row0 * 64 + ((k8 ^ sw0) << 3);
            bf16x8 a0 = *(const bf16x8*)&xs[aidx];
            bf16x8 a1 = *(const bf16x8*)&xs[aidx + 16 * 64];
            int kg = s * 64 + kk * 32 + quad * 8;
            #pragma unroll
            for (int nt = 0; nt < 4; ++nt) {
                bf16x8 b = *(const bf16x8*)&wrow[(size_t)(nt * 16 + lane15) * 256 + kg];
                acc[0][nt] = __builtin_amdgcn_mfma_f32_16x16x32_bf16(a0, b, acc[0][nt], 0, 0, 0);
                acc[1][nt] = __builtin_amdgcn_mfma_f32_16x16x32_bf16(a1, b, acc[1][nt], 0, 0, 0);
            }
        }
    }

    const float* at = at1 + r * 128;
    #pragma unroll
    for (int mt = 0; mt < 2; ++mt) {
        float pi[4] = {0.f, 0.f, 0.f, 0.f};
        float pj[4] = {0.f, 0.f, 0.f, 0.f};
        #pragma unroll
        for (int nt = 0; nt < 4; ++nt) {
            int gcol = nt * 16 + lane15;
            float ai = 0.f, aj = 0.f;
            if (r < 8) { ai = at[gcol]; aj = at[64 + gcol]; }
            #pragma unroll
            for (int reg = 0; reg < 4; ++reg) {
                float v = acc[mt][nt][reg];
                int grow = node0 + w * 32 + mt * 16 + quad * 4 + reg;
                if (grow < N_NODES) {
                    if (r < 8)
                        xr1b[((size_t)r * N_NODES + grow) * 64 + gcol] = f2bf(v);
                    else
                        hrootb[(size_t)grow * 64 + gcol] = f2bf(v);
                }
                pi[reg] += ai * v;
                pj[reg] += aj * v;
            }
        }
        if (r < 8) {
            #pragma unroll
            for (int reg = 0; reg < 4; ++reg) {
                float s_ = pi[reg], u_ = pj[reg];
                #pragma unroll
                for (int off = 1; off < 16; off <<= 1) {
                    s_ += __shfl_xor(s_, off, 64);
                    u_ += __shfl_xor(u_, off, 64);
                }
                if (lane15 == 0) {
                    int grow = node0 + w * 32 + mt * 16 + quad * 4 + reg;
                    if (grow < N_NODES) {
                        si1[r * N_NODES + grow] = s_;
                        sj1[r * N_NODES + grow] = u_;
                    }
                }
            }
        }
    }
}

// ---------- layer 1: color-sort + score + gather + finalize + fused proj2 ----------
// All per-wave LDS state is wave-private; DS ops are in-order per wave -> no
// barriers needed between phases.
__global__ __launch_bounds__(256) void agg1s_kernel(
        const u32* __restrict__ rec, const int* __restrict__ fill,
        const float* __restrict__ si, const float* __restrict__ sj,
        const ushort* __restrict__ xr1b, const ushort* __restrict__ hrootb,
        const float* __restrict__ bias1, ushort* __restrict__ hb,
        const float* __restrict__ W2, const float* __restrict__ at2,
        ushort* __restrict__ xr2b, float* __restrict__ si2,
        float* __restrict__ sj2) {
    __shared__ u32   esrc2[4][CAP];
    __shared__ float ecoef2[4][CAP];
    __shared__ float hval[4][64];
    __shared__ float sden[4][8];
    __shared__ int   scnt[4][8];
    __shared__ int   ccur[4][8];
    __shared__ float ssi[4][8];
    const int t = threadIdx.x;
    const int w = t >> 6, lane = t & 63;
    const int d = blockIdx.x * 4 + w;              // 12500*4 == N_NODES
    if (lane < 8) {
        sden[w][lane] = 0.f; scnt[w][lane] = 0;
        ssi[w][lane] = si[lane * N_NODES + d];
    }
    const int n = min(fill[d], CAP);
    const int base = d * CAP;
    u32 pv[2] = {0, 0};
    // phase 1: read records, count colors
    #pragma unroll
    for (int ii = 0; ii < 2; ++ii) {
        int i = lane + ii * 64;
        if (i < n) {
            u32 rv = rec[base + i];
            pv[ii] = rv;
            atomicAdd(&scnt[w][rv >> 29], 1);
        }
    }
    // exclusive scan of color counts
    if (lane == 0) {
        int o = 0;
        #pragma unroll
        for (int c = 0; c < 8; ++c) { ccur[w][c] = o; o += scnt[w][c]; }
    }
    // placement: counting sort by color
    #pragma unroll
    for (int ii = 0; ii < 2; ++ii) {
        int i = lane + ii * 64;
        if (i < n) {
            int pos = atomicAdd(&ccur[w][pv[ii] >> 29], 1);
            esrc2[w][pos] = pv[ii];
        }
    }
    // phase 2: score sorted list
    float exv[2] = {0.f, 0.f};
    #pragma unroll
    for (int ii = 0; ii < 2; ++ii) {
        int i = lane + ii * 64;
        if (i < n) {
            u32 rv = esrc2[w][i];
            int c = rv >> 29, s = (rv >> 12) & 0x1FFFF;
            float sc = ssi[w][c] + sj[c * N_NODES + s];
            sc = sc > 0.f ? sc : 0.2f * sc;
            float e = __expf(sc);
            exv[ii] = e;
            atomicAdd(&sden[w][c], e);
        }
    }
    #pragma unroll
    for (int ii = 0; ii < 2; ++ii) {
        int i = lane + ii * 64;
        if (i < n) {
            u32 rv = esrc2[w][i];
            int c = rv >> 29;
            float ewf = ((float)(rv & 0xFFF) + 0.5f) * (1.f / 4096.f);
            ecoef2[w][i] = exv[ii] / fmaxf(sden[w][c], 1e-16f)
                           * ewf / (float)scnt[w][c];
        }
    }
    // gather phase: color-clustered, 4-way unrolled
    float a0 = 0.f, a1 = 0.f, a2 = 0.f, a3 = 0.f;
    int i = 0;
    for (; i + 4 <= n; i += 4) {
        u32 p0 = esrc2[w][i],     p1 = esrc2[w][i + 1];
        u32 p2 = esrc2[w][i + 2], p3 = esrc2[w][i + 3];
        float c0 = ecoef2[w][i],     c1 = ecoef2[w][i + 1];
        float c2 = ecoef2[w][i + 2], c3 = ecoef2[w][i + 3];
        int r0 = (p0 >> 29) * N_NODES + ((p0 >> 12) & 0x1FFFF);
        int r1 = (p1 >> 29) * N_NODES + ((p1 >> 12) & 0x1FFFF);
        int r2 = (p2 >> 29) * N_NODES + ((p2 >> 12) & 0x1FFFF);
        int r3 = (p3 >> 29) * N_NODES + ((p3 >> 12) & 0x1FFFF);
        a0 += c0 * bf2f(xr1b[(size_t)r0 * 64 + lane]);
        a1 += c1 * bf2f(xr1b[(size_t)r1 * 64 + lane]);
        a2 += c2 * bf2f(xr1b[(size_t)r2 * 64 + lane]);
        a3 += c3 * bf2f(xr1b[(size_t)r3 * 64 + lane]);
    }
    for (; i < n; ++i) {
        u32 p0 = esrc2[w][i];
        int r0 = (p0 >> 29) * N_NODES + ((p0 >> 12) & 0x1FFFF);
        a0 += ecoef2[w][i] * bf2f(xr1b[(size_t)r0 * 64 + lane]);
    }
    float hf = (a0 + a1) + (a2 + a3)
               + bf2f(hrootb[(size_t)d * 64 + lane]) + bias1[lane];
    hf = fmaxf(hf, 0.f);
    hb[(size_t)d * 64 + lane] = f2bf(hf);
    hval[w][lane] = hf;
    // fused proj2: lane -> (r=lane>>4, c=lane&15) and (r+4, c)
    const int r_ = lane >> 4, c_ = lane & 15;
    float v0 = 0.f, v1 = 0.f;
    #pragma unroll 8
    for (int k = 0; k < 64; ++k) {
        float hk = hval[w][k];
        v0 += hk * W2[((size_t)r_ * 64 + k) * 16 + c_];
        v1 += hk * W2[((size_t)(r_ + 4) * 64 + k) * 16 + c_];
    }
    xr2b[((size_t)r_ * N_NODES + d) * 16 + c_] = f2bf(v0);
    xr2b[((size_t)(r_ + 4) * N_NODES + d) * 16 + c_] = f2bf(v1);
    float s0 = at2[r_ * 32 + c_] * v0,        j0 = at2[r_ * 32 + 16 + c_] * v0;
    float s1 = at2[(r_ + 4) * 32 + c_] * v1,  j1 = at2[(r_ + 4) * 32 + 16 + c_] * v1;
    #pragma unroll
    for (int off = 1; off < 16; off <<= 1) {
        s0 += __shfl_xor(s0, off, 64); j0 += __shfl_xor(j0, off, 64);
        s1 += __shfl_xor(s1, off, 64); j1 += __shfl_xor(j1, off, 64);
    }
    if (c_ == 0) {
        si2[r_ * N_NODES + d] = s0;       sj2[r_ * N_NODES + d] = j0;
        si2[(r_ + 4) * N_NODES + d] = s1; sj2[(r_ + 4) * N_NODES + d] = j1;
    }
}

// ---------- layer 2: color-sort + score + gather + root2 + log_softmax ----------
__global__ __launch_bounds__(256) void agg2s_kernel(
        const u32* __restrict__ rec, const int* __restrict__ fill,
        const float* __restrict__ si, const float* __restrict__ sj,
        const ushort* __restrict__ xr2b, const ushort* __restrict__ hb,
        const float* __restrict__ root2, const float* __restrict__ bias2,
        float* __restrict__ out) {
    __shared__ float rsh[64][17];
    __shared__ float hsh[4][64];
    __shared__ u32   esrc2[4][CAP];
    __shared__ float ecoef2[4][CAP];
    __shared__ float sden[4][8];
    __shared__ int   scnt[4][8];
    __shared__ int   ccur[4][8];
    __shared__ float ssi[4][8];
    const int t = threadIdx.x;
    for (int i = t; i < DIMS * N_CLS; i += 256) rsh[i >> 4][i & 15] = root2[i];
    const int w = t >> 6, lane = t & 63;
    const int d = blockIdx.x * 4 + w;
    hsh[w][lane] = bf2f(hb[(size_t)d * 64 + lane]);
    if (lane < 8) {
        sden[w][lane] = 0.f; scnt[w][lane] = 0;
        ssi[w][lane] = si[lane * N_NODES + d];
    }
    const int n = min(fill[d], CAP);
    const int base = d * CAP;
    u32 pv[2] = {0, 0};
    #pragma unroll
    for (int ii = 0; ii < 2; ++ii) {
        int i = lane + ii * 64;
        if (i < n) {
            u32 rv = rec[base + i];
            pv[ii] = rv;
            atomicAdd(&scnt[w][rv >> 29], 1);
        }
    }
    if (lane == 0) {
        int o = 0;
        #pragma unroll
        for (int c = 0; c < 8; ++c) { ccur[w][c] = o; o += scnt[w][c]; }
    }
    #pragma unroll
    for (int ii = 0; ii < 2; ++ii) {
        int i = lane + ii * 64;
        if (i < n) {
            int pos = atomicAdd(&ccur[w][pv[ii] >> 29], 1);
            esrc2[w][pos] = pv[ii];
        }
    }
    float exv[2] = {0.f, 0.f};
    #pragma unroll
    for (int ii = 0; ii < 2; ++ii) {
        int i = lane + ii * 64;
        if (i < n) {
            u32 rv = esrc2[w][i];
            int c = rv >> 29, s = (rv >> 12) & 0x1FFFF;
            float sc = ssi[w][c] + sj[c * N_NODES + s];
            sc = sc > 0.f ? sc : 0.2f * sc;
            float e = __expf(sc);
            exv[ii] = e;
            atomicAdd(&sden[w][c], e);
        }
    }
    #pragma unroll
    for (int ii = 0; ii < 2; ++ii) {
        int i = lane + ii * 64;
        if (i < n) {
            u32 rv = esrc2[w][i];
            int c = rv >> 29;
            float ewf = ((float)(rv & 0xFFF) + 0.5f) * (1.f / 4096.f);
            ecoef2[w][i] = exv[ii] / fmaxf(sden[w][c], 1e-16f)
                           * ewf / (float)scnt[w][c];
        }
    }
    __syncthreads();                               // rsh cooperative load
    const int sub = lane >> 4, cd = lane & 15;
    float acc = 0.f;
    for (int i = sub; i < n; i += 4) {
        u32 p = esrc2[w][i];
        int row = (p >> 29) * N_NODES + ((p >> 12) & 0x1FFFF);
        acc += ecoef2[w][i] * bf2f(xr2b[(size_t)row * 16 + cd]);
    }
    #pragma unroll
    for (int k0 = 0; k0 < 16; ++k0) {              // root2 contribution
        int k = sub * 16 + k0;
        acc += hsh[w][k] * rsh[k][cd];
    }
    acc += __shfl_xor(acc, 16, 64);
    acc += __shfl_xor(acc, 32, 64);
    if (sub == 0) {
        acc += bias2[cd];
        float m = acc;
        #pragma unroll
        for (int off = 8; off; off >>= 1) m = fmaxf(m, __shfl_xor(m, off, 16));
        float ex2 = expf(acc - m);
        float ssum = ex2;
        #pragma unroll
        for (int off = 8; off; off >>= 1) ssum += __shfl_xor(ssum, off, 16);
        out[(size_t)d * 16 + cd] = acc - m - logf(ssum);
    }
}

extern "C" void kernel_launch(void* const* d_in, const int* in_sizes, int n_in,
                              void* d_out, int out_size, void* d_ws, size_t ws_size,
                              hipStream_t stream) {
    const float* x     = (const float*)d_in[0];
    const int*   ei    = (const int*)  d_in[1];
    const float* ew    = (const float*)d_in[2];
    const int*   ecol  = (const int*)  d_in[3];
    const float* W1    = (const float*)d_in[4];
    const float* at1   = (const float*)d_in[5];
    const float* root1 = (const float*)d_in[6];
    const float* b1    = (const float*)d_in[7];
    const float* W2    = (const float*)d_in[8];
    const float* at2   = (const float*)d_in[9];
    const float* root2 = (const float*)d_in[10];
    const float* b2    = (const float*)d_in[11];
    float* out = (float*)d_out;
    float* ws  = (float*)d_ws;

    // workspace layout (float offsets)
    ushort*   xb    = (ushort*)(ws + 0);           // 12.8M bf16
    ushort*   wt1   = (ushort*)(ws + 6400000);     // 147,456 bf16 [9][64][256]
    ushort*   xr1b  = (ushort*)(ws + 6480000);     // 25.6M bf16 [R,N,64]
    ushort*   hrootb= (ushort*)(ws + 19280000);    // 3.2M bf16
    ushort*   xr2b  = (ushort*)(ws + 20880000);    // 6.4M bf16 [R,N,16]
    float*    si1   = ws + 24080000;               // 400k
    float*    sj1   = ws + 24480000;               // 400k
    float*    si2   = ws + 24880000;               // 400k
    float*    sj2   = ws + 25280000;               // 400k
    int*      fill  = (int*)(ws + 25680000);       // 50k, zeroed
    ushort*   hb    = (ushort*)(ws + 25730000);    // 3.2M bf16
    u32*      rec   = (u32*)(ws + 27330000);       // 4.8M+1 u32

    hipMemsetAsync(fill, 0, (size_t)N_NODES * 4, stream);

    cvt_x_kernel<<<12500, 256, 0, stream>>>(x, xb);
    cvt_w_kernel<<<576, 256, 0, stream>>>(W1, root1, wt1);
    front_kernel<<<FRONT_BLKS, 256, 0, stream>>>(xb, wt1, at1, xr1b, hrootb,
                                                 si1, sj1, ei, ecol, ew, fill, rec);
    agg1s_kernel<<<12500, 256, 0, stream>>>(rec, fill, si1, sj1, xr1b, hrootb,
                                            b1, hb, W2, at2, xr2b, si2, sj2);
    agg2s_kernel<<<12500, 256, 0, stream>>>(rec, fill, si2, sj2, xr2b, hb,
                                            root2, b2, out);
}